// Round 8
// baseline (170.598 us; speedup 1.0000x reference)
//
#include <hip/hip_runtime.h>
#include <hip/hip_bf16.h>
#include <stdint.h>
#include <math.h>

#define SEQ   1024
#define NHEAD 12
#define HD    64
#define CDIM  768
#define MTOK  8192
#define NQKV  2304
#define NPAIR 96   // BS*NHEAD

// q pre-scale: 1/sqrt(64) * log2(e)  (softmax done base-2)
#define QSCALE 0.18033688011112042f

typedef uint16_t u16;
typedef __attribute__((ext_vector_type(8)))  __bf16 bf16x8;
typedef __attribute__((ext_vector_type(4)))  float  f32x4;
typedef __attribute__((ext_vector_type(16))) float  f32x16;

__device__ __forceinline__ u16 f32_to_bf16(float f) {
  union { float f; uint32_t u; } cv; cv.f = f;
  uint32_t u = cv.u;
  return (u16)((u + 0x7FFFu + ((u >> 16) & 1u)) >> 16);
}

__device__ __forceinline__ uint32_t cvt_pk_bf16(float lo, float hi) {
  uint32_t r;
  asm("v_cvt_pk_bf16_f32 %0, %1, %2" : "=v"(r) : "v"(lo), "v"(hi));
  return r;
}

// v_permlane32_swap_b32: a.lo keeps a.lo, a.hi <- b.lo ; b.lo <- a.hi, b.hi keeps b.hi
__device__ __forceinline__ void pl32_swap(uint32_t& a, uint32_t& b) {
  asm volatile("v_permlane32_swap_b32 %0, %1" : "+v"(a), "+v"(b));
}

__device__ __forceinline__ void load_lds16(const u16* g, u16* l) {
  __builtin_amdgcn_global_load_lds(
      (const __attribute__((address_space(1))) uint32_t*)g,
      (__attribute__((address_space(3))) uint32_t*)l, 16, 0, 0);
}

// swizzled LDS read: 16B at (row, col-byte cb) of a 128B-row tile
__device__ __forceinline__ bf16x8 ldsw(const u16* base, int r, int cb) {
  int byte = (r << 7) + cb;
  byte ^= ((r & 7) << 4);
  return *(const bf16x8*)((const char*)base + byte);
}

// stage NB bytes (rows of 128B) from contiguous global, swizzled
template<int NB>
__device__ __forceinline__ void stage_swz(const u16* __restrict__ g, u16* l, int tid) {
  #pragma unroll
  for (int i = 0; i < NB / 4096; ++i) {
    int F = i * 4096 + tid * 16;
    int S = F ^ (((F >> 7) & 7) << 4);
    load_lds16(g + (S >> 1), l + (F >> 1));
  }
}

// stage V^T chunk: global vt[pair][d=64][n=1024], cols kc*64..+63 -> 64x128B tile
__device__ __forceinline__ void stage_vt(const u16* __restrict__ vtb, u16* l, int kc, int tid) {
  #pragma unroll
  for (int i = 0; i < 2; ++i) {
    int F = i * 4096 + tid * 16;
    int S = F ^ (((F >> 7) & 7) << 4);
    int r = S >> 7;
    int cb = S & 127;
    load_lds16(vtb + ((size_t)r << 10) + (kc << 6) + (cb >> 1), l + (F >> 1));
  }
}

// ---- convert x (fp32) -> bf16, 8 elems/thread ----
__global__ __launch_bounds__(256) void cvt_x_kernel(const float* __restrict__ in,
                                                    u16* __restrict__ out) {
  int i = blockIdx.x * 256 + threadIdx.x;
  const float4* p = (const float4*)in + (size_t)i * 2;
  float4 a = p[0], b = p[1];
  uint4 o;
  o.x = cvt_pk_bf16(a.x, a.y);
  o.y = cvt_pk_bf16(a.z, a.w);
  o.z = cvt_pk_bf16(b.x, b.y);
  o.w = cvt_pk_bf16(b.z, b.w);
  ((uint4*)out)[i] = o;
}

// ---- LDS-tiled transpose+convert: in [K][N] fp32 -> out [N][K] bf16 ----
__global__ __launch_bounds__(256) void transpose_cvt_kernel(const float* __restrict__ in,
                                                            u16* __restrict__ out,
                                                            int K, int N) {
  __shared__ u16 t[64][66];
  int nbk = K >> 6;
  int bk = blockIdx.x % nbk, bn = blockIdx.x / nbk;
  int k0 = bk << 6, n0 = bn << 6;
  int tid = threadIdx.x;
  #pragma unroll
  for (int i = 0; i < 16; ++i) {
    int idx = i * 256 + tid;
    int kr = idx >> 6, nc = idx & 63;
    t[kr][nc] = f32_to_bf16(in[(size_t)(k0 + kr) * N + n0 + nc]);
  }
  __syncthreads();
  #pragma unroll
  for (int i = 0; i < 16; ++i) {
    int idx = i * 256 + tid;
    int nr = idx >> 6, kc = idx & 63;
    out[(size_t)(n0 + nr) * K + k0 + kc] = t[kc][nr];
  }
}

// ---- QKV GEMM: 256x256 tile, BK=64, 8 waves (512 thr), m201-style schedule ----
// A[8192][768] @ WqkvT[2304][768]^T -> scatter q (pre-scaled) / k / vT buffers.
// 128KB dynamic LDS, double-buffered; counted vmcnt (never 0 mid-loop);
// 4 quadrant-phases per K-tile, per-phase barrier lockstep; T2 swizzle; T5 setprio.
__global__ __launch_bounds__(512, 2) void gemm256_qkv(const u16* __restrict__ A,
                                                      const u16* __restrict__ Bt,
                                                      u16* __restrict__ qb,
                                                      u16* __restrict__ kb,
                                                      u16* __restrict__ vb) {
  extern __shared__ u16 lds[];
  u16* As0 = lds;            // [256][64] swizzled, slot 0
  u16* As1 = lds + 16384;    // slot 1
  u16* Bs0 = lds + 32768;
  u16* Bs1 = lds + 49152;

  const int K = CDIM;                         // 768, 12 K-tiles
  int bid = blockIdx.x;
  int wgid = (bid & 7) * 36 + (bid >> 3);     // 288 blocks, bijective XCD swizzle
  int tm = wgid / 9, tn = wgid - tm * 9;
  int mBase = tm << 8, nBase = tn << 8;
  int tid = threadIdx.x;
  int lane = tid & 63, wid = tid >> 6;
  int wm = wid >> 2, wn = wid & 3;            // 2M x 4N waves, each 128x64 output
  int lr = lane & 15, lk = lane >> 4;

  auto STAGE = [&](int kt, u16* as, u16* bs) {
    #pragma unroll
    for (int i = 0; i < 4; ++i) {
      int F = i * 8192 + tid * 16;            // byte in 32KB region
      int row = F >> 7;                       // 0..255
      int cb  = (F & 127) ^ ((row & 7) << 4); // pre-swizzled source col byte
      load_lds16(A + (size_t)(mBase + row) * K + kt * 64 + (cb >> 1), &as[F >> 1]);
    }
    #pragma unroll
    for (int i = 0; i < 4; ++i) {
      int F = i * 8192 + tid * 16;
      int row = F >> 7;
      int cb  = (F & 127) ^ ((row & 7) << 4);
      load_lds16(Bt + (size_t)(nBase + row) * K + kt * 64 + (cb >> 1), &bs[F >> 1]);
    }
  };

  f32x4 acc[8][4] = {};

  auto COMPUTE = [&](const u16* as, const u16* bs) {
    #pragma unroll
    for (int ph = 0; ph < 4; ++ph) {
      const int qm = ph >> 1, qn = ph & 1;    // quadrant: 64 rows x 32 cols
      #pragma unroll
      for (int kk = 0; kk < 2; ++kk) {
        bf16x8 af[4], bf[2];
        #pragma unroll
        for (int mi = 0; mi < 4; ++mi)
          af[mi] = ldsw(as, wm * 128 + qm * 64 + mi * 16 + lr, kk * 64 + lk * 16);
        #pragma unroll
        for (int ni = 0; ni < 2; ++ni)
          bf[ni] = ldsw(bs, wn * 64 + qn * 32 + ni * 16 + lr, kk * 64 + lk * 16);
        __builtin_amdgcn_s_setprio(1);
        #pragma unroll
        for (int mi = 0; mi < 4; ++mi)
          #pragma unroll
          for (int ni = 0; ni < 2; ++ni)
            acc[qm * 4 + mi][qn * 2 + ni] =
                __builtin_amdgcn_mfma_f32_16x16x32_bf16(af[mi], bf[ni],
                                                        acc[qm * 4 + mi][qn * 2 + ni], 0, 0, 0);
        __builtin_amdgcn_s_setprio(0);
      }
      __builtin_amdgcn_s_barrier();           // phase lockstep (no data hazard)
    }
  };

  STAGE(0, As0, Bs0);
  STAGE(1, As1, Bs1);                         // 16 loads outstanding

  for (int kt2 = 0; kt2 < 10; kt2 += 2) {
    asm volatile("s_waitcnt vmcnt(8)" ::: "memory");  // slot0 landed; slot1 in flight
    __builtin_amdgcn_s_barrier();
    COMPUTE(As0, Bs0);                        // ends with barrier: slot0 reads done
    STAGE(kt2 + 2, As0, Bs0);
    asm volatile("s_waitcnt vmcnt(8)" ::: "memory");  // slot1 landed; slot0-new in flight
    __builtin_amdgcn_s_barrier();
    COMPUTE(As1, Bs1);
    STAGE(kt2 + 3, As1, Bs1);
  }
  // tail: tiles 10 (slot0) and 11 (slot1), no further staging
  asm volatile("s_waitcnt vmcnt(8)" ::: "memory");
  __builtin_amdgcn_s_barrier();
  COMPUTE(As0, Bs0);
  asm volatile("s_waitcnt vmcnt(0)" ::: "memory");
  __builtin_amdgcn_s_barrier();
  COMPUTE(As1, Bs1);

  // epilogue: scatter q (pre-scaled) / k [pair][n][d], vT [pair][d][n]
  #pragma unroll
  for (int mi = 0; mi < 8; ++mi)
    #pragma unroll
    for (int ni = 0; ni < 4; ++ni)
      #pragma unroll
      for (int j = 0; j < 4; ++j) {
        int m = mBase + wm * 128 + mi * 16 + lk * 4 + j;
        int c = nBase + wn * 64 + ni * 16 + lr;
        float val = acc[mi][ni][j];
        int s = c / CDIM, rem = c - s * CDIM;
        int h = rem >> 6, d = rem & 63;
        int bb = m >> 10, nn = m & 1023;
        size_t pbase = ((size_t)(bb * NHEAD + h)) << 16;
        if (s == 0)      qb[pbase + (nn << 6) + d] = f32_to_bf16(val * QSCALE);
        else if (s == 1) kb[pbase + (nn << 6) + d] = f32_to_bf16(val);
        else             vb[pbase + ((size_t)d << 10) + nn] = f32_to_bf16(val);
      }
}

// ---- bf16 GEMM (w_o projection), 128x128 tile, BK=64, 4 waves ----
__global__ __launch_bounds__(256) void gemm_bt(const u16* __restrict__ A,
                                               const u16* __restrict__ Bt,
                                               float* __restrict__ Cf,
                                               int M, int N, int K, int cpx) {
  __shared__ u16 As[2][128 * 64];
  __shared__ u16 Bs[2][128 * 64];

  int bid = blockIdx.x;
  int wgid = (bid & 7) * cpx + (bid >> 3);
  const int ntn = N >> 7;
  int tm = wgid / ntn, tn = wgid - tm * ntn;
  int mBase = tm << 7, nBase = tn << 7;
  int tid = threadIdx.x;
  int lane = tid & 63, wid = tid >> 6;
  int wr = (wid >> 1) << 6, wc = (wid & 1) << 6;
  int lr = lane & 15, lk = lane >> 4;

  const int nk = K >> 6;

  auto STAGE = [&](int kt, int b) {
    #pragma unroll
    for (int i = 0; i < 4; ++i) {
      int F = i * 4096 + tid * 16;
      int row = F >> 7;
      int cb  = (F & 127) ^ ((row & 7) << 4);
      load_lds16(A + (size_t)(mBase + row) * K + kt * 64 + (cb >> 1), &As[b][F >> 1]);
    }
    #pragma unroll
    for (int i = 0; i < 4; ++i) {
      int F = i * 4096 + tid * 16;
      int row = F >> 7;
      int cb  = (F & 127) ^ ((row & 7) << 4);
      load_lds16(Bt + (size_t)(nBase + row) * K + kt * 64 + (cb >> 1), &Bs[b][F >> 1]);
    }
  };

  f32x4 acc[4][4] = {};

  STAGE(0, 0);
  for (int kt = 0; kt < nk; ++kt) {
    const int cur = kt & 1;
    if (kt + 1 < nk) {
      STAGE(kt + 1, cur ^ 1);
      asm volatile("s_waitcnt vmcnt(8)" ::: "memory");
    } else {
      asm volatile("s_waitcnt vmcnt(0)" ::: "memory");
    }
    __builtin_amdgcn_s_barrier();
    asm volatile("" ::: "memory");

    #pragma unroll
    for (int kk = 0; kk < 2; ++kk) {
      bf16x8 af[4], bfr[4];
      #pragma unroll
      for (int i = 0; i < 4; ++i)
        af[i]  = ldsw(As[cur], wr + i * 16 + lr, kk * 64 + lk * 16);
      #pragma unroll
      for (int i = 0; i < 4; ++i)
        bfr[i] = ldsw(Bs[cur], wc + i * 16 + lr, kk * 64 + lk * 16);
      #pragma unroll
      for (int mi = 0; mi < 4; ++mi)
        #pragma unroll
        for (int ni = 0; ni < 4; ++ni)
          acc[mi][ni] = __builtin_amdgcn_mfma_f32_16x16x32_bf16(af[mi], bfr[ni], acc[mi][ni], 0, 0, 0);
    }

    __builtin_amdgcn_s_barrier();
    asm volatile("" ::: "memory");
  }

  #pragma unroll
  for (int mi = 0; mi < 4; ++mi)
    #pragma unroll
    for (int ni = 0; ni < 4; ++ni)
      #pragma unroll
      for (int j = 0; j < 4; ++j) {
        int m = mBase + wr + mi * 16 + lk * 4 + j;
        int c = nBase + wc + ni * 16 + lr;
        Cf[(size_t)m * N + c] = acc[mi][ni][j];
      }
}

// ---- flash attention v4: 32x32 swapped QK^T, fully in-register softmax+P ----
__global__ __launch_bounds__(256) void attn_kernel(const u16* __restrict__ q,
                                                   const u16* __restrict__ k,
                                                   const u16* __restrict__ v,
                                                   u16* __restrict__ out) {
  __shared__ u16 Ks[2][64 * 64];
  __shared__ u16 Vs[2][64 * 64];    // V^T chunks: [d=64][k=64]

  int bid = blockIdx.x;
  int wgid = (bid & 7) * 96 + (bid >> 3);   // 768 blocks, 96/XCD -> pairs XCD-local
  int pair = wgid >> 3;
  int qt   = wgid & 7;                      // 8 q-tiles of 128 rows
  int b = pair / NHEAD, hh = pair - b * NHEAD;
  const u16* Kg  = k + ((size_t)pair << 16);
  const u16* Vtb = v + ((size_t)pair << 16);
  int tid = threadIdx.x, lane = tid & 63, wid = tid >> 6;
  int ql = lane & 31, hi = lane >> 5;

  // Q fragments direct to registers (once): row = qt*128 + wid*32 + ql
  const u16* Qrow = q + ((size_t)pair << 16) + (size_t)((qt << 7) + (wid << 5) + ql) * 64;
  bf16x8 qf[4];
  #pragma unroll
  for (int t = 0; t < 4; ++t)
    qf[t] = *(const bf16x8*)(Qrow + t * 16 + hi * 8);

  stage_swz<8192>(Kg, Ks[0], tid);
  stage_vt(Vtb, Vs[0], 0, tid);
  __syncthreads();

  float m_ = -1e30f, l_ = 0.f;   // per-lane: q = ql, k-half = hi (l_ partial)
  f32x16 acc0 = {}, acc1 = {};   // O[q][d]: d-tile 0 (0..31), 1 (32..63)

  for (int kc = 0; kc < 16; ++kc) {
    const int cur = kc & 1;
    if (kc < 15) {
      stage_swz<8192>(Kg + ((kc + 1) << 12), Ks[cur ^ 1], tid);
      stage_vt(Vtb, Vs[cur ^ 1], kc + 1, tid);
    }

    // S^T = K Q^T : 2 k-tiles x 4 d-steps of 32x32x16
    f32x16 s0 = {}, s1 = {};
    __builtin_amdgcn_s_setprio(1);
    #pragma unroll
    for (int t = 0; t < 4; ++t) {
      bf16x8 k0 = ldsw(Ks[cur], ql,      t * 32 + hi * 16);
      s0 = __builtin_amdgcn_mfma_f32_32x32x16_bf16(k0, qf[t], s0, 0, 0, 0);
      bf16x8 k1 = ldsw(Ks[cur], 32 + ql, t * 32 + hi * 16);
      s1 = __builtin_amdgcn_mfma_f32_32x32x16_bf16(k1, qf[t], s1, 0, 0, 0);
    }
    __builtin_amdgcn_s_setprio(0);

    // per-lane partial max over this lane's 32 k-values (all same q)
    float pm = fmaxf(s0[0], s0[1]);
    #pragma unroll
    for (int r = 2; r < 16; ++r) pm = fmaxf(pm, s0[r]);
    #pragma unroll
    for (int r = 0; r < 16; ++r) pm = fmaxf(pm, s1[r]);

    // defer-max: if every lane's partial max is within m_+8, the full row
    // max is too (row max = max of the 2 hi-lanes' partials) -> skip rescale
    if (!__all(pm - m_ <= 8.f)) {
      float om = fmaxf(pm, __shfl_xor(pm, 32, 64));
      float newm = fmaxf(m_, om);
      float alpha = exp2f(m_ - newm);
      m_ = newm;
      l_ *= alpha;
      #pragma unroll
      for (int r = 0; r < 16; ++r) {
        int qr = (r & 3) + 8 * (r >> 2) + 4 * hi;
        float ar = __shfl(alpha, qr, 32);
        acc0[r] *= ar;
        acc1[r] *= ar;
      }
    }

    #pragma unroll
    for (int r = 0; r < 16; ++r) s0[r] = exp2f(s0[r] - m_);
    #pragma unroll
    for (int r = 0; r < 16; ++r) s1[r] = exp2f(s1[r] - m_);

    // partial row-sum (this lane's 32 values), tree
    {
      f32x16 ss = s0 + s1;
      float a0 = (ss[0] + ss[1]) + (ss[2] + ss[3]);
      float a1 = (ss[4] + ss[5]) + (ss[6] + ss[7]);
      float a2 = (ss[8] + ss[9]) + (ss[10] + ss[11]);
      float a3 = (ss[12] + ss[13]) + (ss[14] + ss[15]);
      l_ += (a0 + a1) + (a2 + a3);
    }

    // PV: per k-step t, assemble P A-frag in-register and MFMA both d-tiles
    __builtin_amdgcn_s_setprio(1);
    #pragma unroll
    for (int t = 0; t < 4; ++t) {
      const int base = (t & 1) * 8;
      uint32_t wA, wB, wC, wD;
      if (t < 2) {
        wA = cvt_pk_bf16(s0[base + 0], s0[base + 1]);
        wB = cvt_pk_bf16(s0[base + 2], s0[base + 3]);
        wC = cvt_pk_bf16(s0[base + 4], s0[base + 5]);
        wD = cvt_pk_bf16(s0[base + 6], s0[base + 7]);
      } else {
        wA = cvt_pk_bf16(s1[base + 0], s1[base + 1]);
        wB = cvt_pk_bf16(s1[base + 2], s1[base + 3]);
        wC = cvt_pk_bf16(s1[base + 4], s1[base + 5]);
        wD = cvt_pk_bf16(s1[base + 6], s1[base + 7]);
      }
      pl32_swap(wA, wC);
      pl32_swap(wB, wD);
      union { uint32_t u[4]; bf16x8 v8; } pu;
      pu.u[0] = wA; pu.u[1] = wB; pu.u[2] = wC; pu.u[3] = wD;
      bf16x8 v0 = ldsw(Vs[cur], ql,      t * 32 + hi * 16);
      acc0 = __builtin_amdgcn_mfma_f32_32x32x16_bf16(pu.v8, v0, acc0, 0, 0, 0);
      bf16x8 v1 = ldsw(Vs[cur], 32 + ql, t * 32 + hi * 16);
      acc1 = __builtin_amdgcn_mfma_f32_32x32x16_bf16(pu.v8, v1, acc1, 0, 0, 0);
    }
    __builtin_amdgcn_s_setprio(0);
    __syncthreads();
  }

  // epilogue: full row-sum, normalize, write bf16 attn_out [tok][c]
  l_ += __shfl_xor(l_, 32, 64);
  float il = 1.f / l_;
  u16* ob = out + ((size_t)(b * SEQ + (qt << 7) + (wid << 5))) * CDIM + hh * 64 + ql;
  #pragma unroll
  for (int r = 0; r < 16; ++r) {
    int qr = (r & 3) + 8 * (r >> 2) + 4 * hi;
    float ilr = __shfl(il, qr, 32);
    ob[(size_t)qr * CDIM]      = f32_to_bf16(acc0[r] * ilr);
    ob[(size_t)qr * CDIM + 32] = f32_to_bf16(acc1[r] * ilr);
  }
}

extern "C" void kernel_launch(void* const* d_in, const int* in_sizes, int n_in,
                              void* d_out, int out_size, void* d_ws, size_t ws_size,
                              hipStream_t stream) {
  const float* x     = (const float*)d_in[0];
  const float* w_qkv = (const float*)d_in[1];
  const float* w_o   = (const float*)d_in[2];
  float* out = (float*)d_out;

  u16* xb    = (u16*)d_ws;
  u16* wqkvT = xb    + (size_t)MTOK * CDIM;
  u16* woT   = wqkvT + (size_t)NQKV * CDIM;
  u16* qb    = woT   + (size_t)CDIM * CDIM;
  u16* kb    = qb    + (size_t)NPAIR * SEQ * HD;
  u16* vb    = kb    + (size_t)NPAIR * SEQ * HD;   // stored transposed: [pair][d][n]
  u16* ao    = vb    + (size_t)NPAIR * SEQ * HD;

  // opt-in to 128KB dynamic LDS for the 256^2 GEMM (idempotent)
  (void)hipFuncSetAttribute((const void*)gemm256_qkv,
                            hipFuncAttributeMaxDynamicSharedMemorySize, 131072);

  cvt_x_kernel<<<dim3((MTOK * CDIM) / (256 * 8)), 256, 0, stream>>>(x, xb);
  transpose_cvt_kernel<<<dim3((CDIM / 64) * (NQKV / 64)), 256, 0, stream>>>(w_qkv, wqkvT, CDIM, NQKV);
  transpose_cvt_kernel<<<dim3((CDIM / 64) * (CDIM / 64)), 256, 0, stream>>>(w_o, woT, CDIM, CDIM);

  gemm256_qkv<<<dim3(288), 512, 131072, stream>>>(xb, wqkvT, qb, kb, vb);

  attn_kernel<<<dim3(NPAIR * 8), 256, 0, stream>>>(qb, kb, vb, ao);

  {
    int nwg = (MTOK / 128) * (CDIM / 128);   // 384, %8==0
    gemm_bt<<<dim3(nwg), 256, 0, stream>>>(
        ao, woT, out, MTOK, CDIM, CDIM, nwg / 8);
  }
}

// Round 9
// 160.359 us; speedup vs baseline: 1.0639x; 1.0639x over previous
//
#include <hip/hip_runtime.h>
#include <hip/hip_bf16.h>
#include <stdint.h>
#include <math.h>

#define SEQ   1024
#define NHEAD 12
#define HD    64
#define CDIM  768
#define MTOK  8192
#define NQKV  2304
#define NPAIR 96   // BS*NHEAD

// q pre-scale: 1/sqrt(64) * log2(e)  (softmax done base-2)
#define QSCALE 0.18033688011112042f

typedef uint16_t u16;
typedef __attribute__((ext_vector_type(8)))  __bf16 bf16x8;
typedef __attribute__((ext_vector_type(4)))  float  f32x4;
typedef __attribute__((ext_vector_type(16))) float  f32x16;

__device__ __forceinline__ u16 f32_to_bf16(float f) {
  union { float f; uint32_t u; } cv; cv.f = f;
  uint32_t u = cv.u;
  return (u16)((u + 0x7FFFu + ((u >> 16) & 1u)) >> 16);
}

__device__ __forceinline__ uint32_t cvt_pk_bf16(float lo, float hi) {
  uint32_t r;
  asm("v_cvt_pk_bf16_f32 %0, %1, %2" : "=v"(r) : "v"(lo), "v"(hi));
  return r;
}

// v_permlane32_swap_b32: a.hi <-> b.lo (pure, schedulable)
__device__ __forceinline__ void pl32_swap(uint32_t& a, uint32_t& b) {
  asm("v_permlane32_swap_b32 %0, %1" : "+v"(a), "+v"(b));
}

__device__ __forceinline__ void load_lds16(const u16* g, u16* l) {
  __builtin_amdgcn_global_load_lds(
      (const __attribute__((address_space(1))) uint32_t*)g,
      (__attribute__((address_space(3))) uint32_t*)l, 16, 0, 0);
}

// swizzled LDS read: 16B at (row, col-byte cb) of a 128B-row tile
__device__ __forceinline__ bf16x8 ldsw(const u16* base, int r, int cb) {
  int byte = (r << 7) + cb;
  byte ^= ((r & 7) << 4);
  return *(const bf16x8*)((const char*)base + byte);
}

// ---- convert x (fp32) -> bf16, 8 elems/thread ----
__global__ __launch_bounds__(256) void cvt_x_kernel(const float* __restrict__ in,
                                                    u16* __restrict__ out) {
  int i = blockIdx.x * 256 + threadIdx.x;
  const float4* p = (const float4*)in + (size_t)i * 2;
  float4 a = p[0], b = p[1];
  uint4 o;
  o.x = cvt_pk_bf16(a.x, a.y);
  o.y = cvt_pk_bf16(a.z, a.w);
  o.z = cvt_pk_bf16(b.x, b.y);
  o.w = cvt_pk_bf16(b.z, b.w);
  ((uint4*)out)[i] = o;
}

// ---- LDS-tiled transpose+convert: in [K][N] fp32 -> out [N][K] bf16 ----
__global__ __launch_bounds__(256) void transpose_cvt_kernel(const float* __restrict__ in,
                                                            u16* __restrict__ out,
                                                            int K, int N) {
  __shared__ u16 t[64][66];
  int nbk = K >> 6;
  int bk = blockIdx.x % nbk, bn = blockIdx.x / nbk;
  int k0 = bk << 6, n0 = bn << 6;
  int tid = threadIdx.x;
  #pragma unroll
  for (int i = 0; i < 16; ++i) {
    int idx = i * 256 + tid;
    int kr = idx >> 6, nc = idx & 63;
    t[kr][nc] = f32_to_bf16(in[(size_t)(k0 + kr) * N + n0 + nc]);
  }
  __syncthreads();
  #pragma unroll
  for (int i = 0; i < 16; ++i) {
    int idx = i * 256 + tid;
    int nr = idx >> 6, kc = idx & 63;
    out[(size_t)(n0 + nr) * K + k0 + kc] = t[kc][nr];
  }
}

// ---- bf16 GEMM, A[M][K] @ Bt[N][K]^T, 128x128 tile, BK=64, 4 waves ----
// SINGLE-buffered 32KB LDS (m97 structure: residency-powered overlap),
// T2 read swizzle, T1 XCD swizzle. 2 barriers per K-step.
// EPI 0: scatter q (pre-scaled) / k [pair][n][d], vT [pair][d][n]
// EPI 1: plain fp32 store
template<int EPI>
__global__ __launch_bounds__(256) void gemm_bt(const u16* __restrict__ A,
                                               const u16* __restrict__ Bt,
                                               float* __restrict__ Cf,
                                               u16* __restrict__ qb,
                                               u16* __restrict__ kb,
                                               u16* __restrict__ vb,
                                               int M, int N, int K, int cpx) {
  __shared__ u16 As[128 * 64];
  __shared__ u16 Bs[128 * 64];

  int bid = blockIdx.x;
  int wgid = (bid & 7) * cpx + (bid >> 3);
  const int ntn = N >> 7;
  int tm = wgid / ntn, tn = wgid - tm * ntn;
  int mBase = tm << 7, nBase = tn << 7;
  int tid = threadIdx.x;
  int lane = tid & 63, wid = tid >> 6;
  int wr = (wid >> 1) << 6, wc = (wid & 1) << 6;
  int lr = lane & 15, lk = lane >> 4;

  const int nk = K >> 6;

  auto STAGE = [&](int kt) {
    #pragma unroll
    for (int i = 0; i < 4; ++i) {
      int F = i * 4096 + tid * 16;
      int row = F >> 7;
      int cb  = (F & 127) ^ ((row & 7) << 4);
      load_lds16(A + (size_t)(mBase + row) * K + kt * 64 + (cb >> 1), &As[F >> 1]);
    }
    #pragma unroll
    for (int i = 0; i < 4; ++i) {
      int F = i * 4096 + tid * 16;
      int row = F >> 7;
      int cb  = (F & 127) ^ ((row & 7) << 4);
      load_lds16(Bt + (size_t)(nBase + row) * K + kt * 64 + (cb >> 1), &Bs[F >> 1]);
    }
  };

  f32x4 acc[4][4] = {};

  STAGE(0);
  for (int kt = 0; kt < nk; ++kt) {
    asm volatile("s_waitcnt vmcnt(0)" ::: "memory");
    __builtin_amdgcn_s_barrier();
    asm volatile("" ::: "memory");

    #pragma unroll
    for (int kk = 0; kk < 2; ++kk) {
      bf16x8 af[4], bfr[4];
      #pragma unroll
      for (int i = 0; i < 4; ++i)
        af[i]  = ldsw(As, wr + i * 16 + lr, kk * 64 + lk * 16);
      #pragma unroll
      for (int i = 0; i < 4; ++i)
        bfr[i] = ldsw(Bs, wc + i * 16 + lr, kk * 64 + lk * 16);
      #pragma unroll
      for (int mi = 0; mi < 4; ++mi)
        #pragma unroll
        for (int ni = 0; ni < 4; ++ni)
          acc[mi][ni] = __builtin_amdgcn_mfma_f32_16x16x32_bf16(af[mi], bfr[ni], acc[mi][ni], 0, 0, 0);
    }

    __builtin_amdgcn_s_barrier();   // all reads of As/Bs consumed
    asm volatile("" ::: "memory");
    if (kt + 1 < nk) STAGE(kt + 1); // overwrite is now safe; latency overlaps other blocks
  }

  #pragma unroll
  for (int mi = 0; mi < 4; ++mi)
    #pragma unroll
    for (int ni = 0; ni < 4; ++ni)
      #pragma unroll
      for (int j = 0; j < 4; ++j) {
        int m = mBase + wr + mi * 16 + lk * 4 + j;
        int c = nBase + wc + ni * 16 + lr;
        float val = acc[mi][ni][j];
        if (EPI == 0) {
          int s = c / CDIM, rem = c - s * CDIM;
          int h = rem >> 6, d = rem & 63;
          int bb = m >> 10, nn = m & 1023;
          size_t pbase = ((size_t)(bb * NHEAD + h)) << 16;
          if (s == 0)      qb[pbase + (nn << 6) + d] = f32_to_bf16(val * QSCALE);
          else if (s == 1) kb[pbase + (nn << 6) + d] = f32_to_bf16(val);
          else             vb[pbase + ((size_t)d << 10) + nn] = f32_to_bf16(val);
        } else {
          Cf[(size_t)m * N + c] = val;
        }
      }
}

// ---- flash attention v5: QBLK=64, 2 waves x 32 q-rows, single-buffer KV ----
// 1536 blocks -> 6 blocks/CU; 16KB LDS; in-register softmax+P (v4 math);
// 32x32 swapped QK^T; XCD-chunked so each pair's 16 blocks share one L2.
__global__ __launch_bounds__(128) void attn_kernel(const u16* __restrict__ q,
                                                   const u16* __restrict__ k,
                                                   const u16* __restrict__ v,
                                                   u16* __restrict__ out) {
  __shared__ u16 Ks[64 * 64];
  __shared__ u16 Vs[64 * 64];     // V^T chunk: [d=64][k=64]

  int bid = blockIdx.x;
  int wgid = (bid & 7) * 192 + (bid >> 3);  // 1536 blocks, 192/XCD -> pairs XCD-local
  int pair = wgid >> 4;
  int qt   = wgid & 15;                     // 16 q-tiles of 64 rows
  int b = pair / NHEAD, hh = pair - b * NHEAD;
  const u16* Kg  = k + ((size_t)pair << 16);
  const u16* Vtb = v + ((size_t)pair << 16);
  int tid = threadIdx.x, lane = tid & 63, wid = tid >> 6;  // wid 0..1
  int ql = lane & 31, hi = lane >> 5;

  // Q fragments direct to registers (once): row = qt*64 + wid*32 + ql
  const u16* Qrow = q + ((size_t)pair << 16) + (size_t)((qt << 6) + (wid << 5) + ql) * 64;
  bf16x8 qf[4];
  #pragma unroll
  for (int t = 0; t < 4; ++t)
    qf[t] = *(const bf16x8*)(Qrow + t * 16 + hi * 8);

  // stage K chunk (swizzled) with 128 threads: 4 iters x 2KB
  auto STAGEK = [&](int kc) {
    #pragma unroll
    for (int i = 0; i < 4; ++i) {
      int F = i * 2048 + tid * 16;
      int S = F ^ (((F >> 7) & 7) << 4);
      load_lds16(Kg + (kc << 12) + (S >> 1), Ks + (F >> 1));
    }
  };
  auto STAGEV = [&](int kc) {
    #pragma unroll
    for (int i = 0; i < 4; ++i) {
      int F = i * 2048 + tid * 16;
      int S = F ^ (((F >> 7) & 7) << 4);
      int r = S >> 7, cb = S & 127;
      load_lds16(Vtb + ((size_t)r << 10) + (kc << 6) + (cb >> 1), Vs + (F >> 1));
    }
  };

  float m_ = -1e30f, l_ = 0.f;   // per-lane: q = ql, k-half = hi (l_ partial)
  f32x16 acc0 = {}, acc1 = {};   // O[q][d]: d-tile 0 (0..31), 1 (32..63)

  STAGEK(0); STAGEV(0);
  for (int kc = 0; kc < 16; ++kc) {
    asm volatile("s_waitcnt vmcnt(0)" ::: "memory");
    __builtin_amdgcn_s_barrier();
    asm volatile("" ::: "memory");

    // S^T = K Q^T : 2 k-tiles x 4 d-steps of 32x32x16
    f32x16 s0 = {}, s1 = {};
    __builtin_amdgcn_s_setprio(1);
    #pragma unroll
    for (int t = 0; t < 4; ++t) {
      bf16x8 k0 = ldsw(Ks, ql,      t * 32 + hi * 16);
      s0 = __builtin_amdgcn_mfma_f32_32x32x16_bf16(k0, qf[t], s0, 0, 0, 0);
      bf16x8 k1 = ldsw(Ks, 32 + ql, t * 32 + hi * 16);
      s1 = __builtin_amdgcn_mfma_f32_32x32x16_bf16(k1, qf[t], s1, 0, 0, 0);
    }
    __builtin_amdgcn_s_setprio(0);

    // V fragments for this chunk (LDS reads issue now, consumed in PV)
    bf16x8 vf0[4], vf1[4];
    #pragma unroll
    for (int t = 0; t < 4; ++t) {
      vf0[t] = ldsw(Vs, ql,      t * 32 + hi * 16);
      vf1[t] = ldsw(Vs, 32 + ql, t * 32 + hi * 16);
    }

    // per-lane partial max over this lane's 32 k-values (all same q)
    float pm = fmaxf(s0[0], s0[1]);
    #pragma unroll
    for (int r = 2; r < 16; ++r) pm = fmaxf(pm, s0[r]);
    #pragma unroll
    for (int r = 0; r < 16; ++r) pm = fmaxf(pm, s1[r]);

    // defer-max: rescale only when some row's max grew by > 8 (log2 units)
    if (!__all(pm - m_ <= 8.f)) {
      float om = fmaxf(pm, __shfl_xor(pm, 32, 64));
      float newm = fmaxf(m_, om);
      float alpha = exp2f(m_ - newm);
      m_ = newm;
      l_ *= alpha;
      #pragma unroll
      for (int r = 0; r < 16; ++r) {
        int qr = (r & 3) + 8 * (r >> 2) + 4 * hi;
        float ar = __shfl(alpha, qr, 32);
        acc0[r] *= ar;
        acc1[r] *= ar;
      }
    }

    #pragma unroll
    for (int r = 0; r < 16; ++r) s0[r] = exp2f(s0[r] - m_);
    #pragma unroll
    for (int r = 0; r < 16; ++r) s1[r] = exp2f(s1[r] - m_);

    // partial row-sum (this lane's 32 values), tree
    {
      f32x16 ss = s0 + s1;
      float a0 = (ss[0] + ss[1]) + (ss[2] + ss[3]);
      float a1 = (ss[4] + ss[5]) + (ss[6] + ss[7]);
      float a2 = (ss[8] + ss[9]) + (ss[10] + ss[11]);
      float a3 = (ss[12] + ss[13]) + (ss[14] + ss[15]);
      l_ += (a0 + a1) + (a2 + a3);
    }

    // PV: per k-step t, assemble P A-frag in-register and MFMA both d-tiles
    __builtin_amdgcn_s_setprio(1);
    #pragma unroll
    for (int t = 0; t < 4; ++t) {
      const int base = (t & 1) * 8;
      uint32_t wA, wB, wC, wD;
      if (t < 2) {
        wA = cvt_pk_bf16(s0[base + 0], s0[base + 1]);
        wB = cvt_pk_bf16(s0[base + 2], s0[base + 3]);
        wC = cvt_pk_bf16(s0[base + 4], s0[base + 5]);
        wD = cvt_pk_bf16(s0[base + 6], s0[base + 7]);
      } else {
        wA = cvt_pk_bf16(s1[base + 0], s1[base + 1]);
        wB = cvt_pk_bf16(s1[base + 2], s1[base + 3]);
        wC = cvt_pk_bf16(s1[base + 4], s1[base + 5]);
        wD = cvt_pk_bf16(s1[base + 6], s1[base + 7]);
      }
      pl32_swap(wA, wC);
      pl32_swap(wB, wD);
      union { uint32_t u[4]; bf16x8 v8; } pu;
      pu.u[0] = wA; pu.u[1] = wB; pu.u[2] = wC; pu.u[3] = wD;
      acc0 = __builtin_amdgcn_mfma_f32_32x32x16_bf16(pu.v8, vf0[t], acc0, 0, 0, 0);
      acc1 = __builtin_amdgcn_mfma_f32_32x32x16_bf16(pu.v8, vf1[t], acc1, 0, 0, 0);
    }
    __builtin_amdgcn_s_setprio(0);

    __builtin_amdgcn_s_barrier();   // Ks/Vs reads consumed by both waves
    asm volatile("" ::: "memory");
    if (kc < 15) { STAGEK(kc + 1); STAGEV(kc + 1); }
  }

  // epilogue: full row-sum, normalize, write bf16 attn_out [tok][c]
  l_ += __shfl_xor(l_, 32, 64);
  float il = 1.f / l_;
  u16* ob = out + ((size_t)(b * SEQ + (qt << 6) + (wid << 5))) * CDIM + hh * 64 + ql;
  #pragma unroll
  for (int r = 0; r < 16; ++r) {
    int qr = (r & 3) + 8 * (r >> 2) + 4 * hi;
    float ilr = __shfl(il, qr, 32);
    ob[(size_t)qr * CDIM]      = f32_to_bf16(acc0[r] * ilr);
    ob[(size_t)qr * CDIM + 32] = f32_to_bf16(acc1[r] * ilr);
  }
}

extern "C" void kernel_launch(void* const* d_in, const int* in_sizes, int n_in,
                              void* d_out, int out_size, void* d_ws, size_t ws_size,
                              hipStream_t stream) {
  const float* x     = (const float*)d_in[0];
  const float* w_qkv = (const float*)d_in[1];
  const float* w_o   = (const float*)d_in[2];
  float* out = (float*)d_out;

  u16* xb    = (u16*)d_ws;
  u16* wqkvT = xb    + (size_t)MTOK * CDIM;
  u16* woT   = wqkvT + (size_t)NQKV * CDIM;
  u16* qb    = woT   + (size_t)CDIM * CDIM;
  u16* kb    = qb    + (size_t)NPAIR * SEQ * HD;
  u16* vb    = kb    + (size_t)NPAIR * SEQ * HD;   // stored transposed: [pair][d][n]
  u16* ao    = vb    + (size_t)NPAIR * SEQ * HD;

  cvt_x_kernel<<<dim3((MTOK * CDIM) / (256 * 8)), 256, 0, stream>>>(x, xb);
  transpose_cvt_kernel<<<dim3((CDIM / 64) * (NQKV / 64)), 256, 0, stream>>>(w_qkv, wqkvT, CDIM, NQKV);
  transpose_cvt_kernel<<<dim3((CDIM / 64) * (CDIM / 64)), 256, 0, stream>>>(w_o, woT, CDIM, CDIM);

  {
    int nwg = (MTOK / 128) * (NQKV / 128);   // 1152, %8==0
    gemm_bt<0><<<dim3(nwg), 256, 0, stream>>>(
        xb, wqkvT, nullptr, qb, kb, vb, MTOK, NQKV, CDIM, nwg / 8);
  }

  attn_kernel<<<dim3(NPAIR * 16), 128, 0, stream>>>(qb, kb, vb, ao);

  {
    int nwg = (MTOK / 128) * (CDIM / 128);   // 384, %8==0
    gemm_bt<1><<<dim3(nwg), 256, 0, stream>>>(
        ao, woT, out, nullptr, nullptr, nullptr, MTOK, CDIM, CDIM, nwg / 8);
  }
}

// Round 10
// 147.579 us; speedup vs baseline: 1.1560x; 1.0866x over previous
//
#include <hip/hip_runtime.h>
#include <hip/hip_bf16.h>
#include <stdint.h>
#include <math.h>

#define SEQ   1024
#define NHEAD 12
#define HD    64
#define CDIM  768
#define MTOK  8192
#define NQKV  2304
#define NPAIR 96   // BS*NHEAD

// q pre-scale: 1/sqrt(64) * log2(e)  (softmax done base-2)
#define QSCALE 0.18033688011112042f

typedef uint16_t u16;
typedef __attribute__((ext_vector_type(8)))  __bf16 bf16x8;
typedef __attribute__((ext_vector_type(4)))  float  f32x4;
typedef __attribute__((ext_vector_type(16))) float  f32x16;

__device__ __forceinline__ u16 f32_to_bf16(float f) {
  union { float f; uint32_t u; } cv; cv.f = f;
  uint32_t u = cv.u;
  return (u16)((u + 0x7FFFu + ((u >> 16) & 1u)) >> 16);
}

__device__ __forceinline__ uint32_t cvt_pk_bf16(float lo, float hi) {
  uint32_t r;
  asm("v_cvt_pk_bf16_f32 %0, %1, %2" : "=v"(r) : "v"(lo), "v"(hi));
  return r;
}

// v_permlane32_swap_b32: a.hi <-> b.lo
__device__ __forceinline__ void pl32_swap(uint32_t& a, uint32_t& b) {
  asm("v_permlane32_swap_b32 %0, %1" : "+v"(a), "+v"(b));
}

__device__ __forceinline__ void load_lds16(const u16* g, u16* l) {
  __builtin_amdgcn_global_load_lds(
      (const __attribute__((address_space(1))) uint32_t*)g,
      (__attribute__((address_space(3))) uint32_t*)l, 16, 0, 0);
}

// swizzled LDS read: 16B at (row, col-byte cb) of a 128B-row tile
__device__ __forceinline__ bf16x8 ldsw(const u16* base, int r, int cb) {
  int byte = (r << 7) + cb;
  byte ^= ((r & 7) << 4);
  return *(const bf16x8*)((const char*)base + byte);
}

// stage NB bytes (rows of 128B) from contiguous global, swizzled
template<int NB>
__device__ __forceinline__ void stage_swz(const u16* __restrict__ g, u16* l, int tid) {
  #pragma unroll
  for (int i = 0; i < NB / 4096; ++i) {
    int F = i * 4096 + tid * 16;
    int S = F ^ (((F >> 7) & 7) << 4);
    load_lds16(g + (S >> 1), l + (F >> 1));
  }
}

// stage V^T chunk: global vt[pair][d=64][n=1024], cols kc*64..+63 -> 64x128B tile
__device__ __forceinline__ void stage_vt(const u16* __restrict__ vtb, u16* l, int kc, int tid) {
  #pragma unroll
  for (int i = 0; i < 2; ++i) {
    int F = i * 4096 + tid * 16;
    int S = F ^ (((F >> 7) & 7) << 4);
    int r = S >> 7;
    int cb = S & 127;
    load_lds16(vtb + ((size_t)r << 10) + (kc << 6) + (cb >> 1), l + (F >> 1));
  }
}

// ---- convert x (fp32) -> bf16, 8 elems/thread ----
__global__ __launch_bounds__(256) void cvt_x_kernel(const float* __restrict__ in,
                                                    u16* __restrict__ out) {
  int i = blockIdx.x * 256 + threadIdx.x;
  const float4* p = (const float4*)in + (size_t)i * 2;
  float4 a = p[0], b = p[1];
  uint4 o;
  o.x = cvt_pk_bf16(a.x, a.y);
  o.y = cvt_pk_bf16(a.z, a.w);
  o.z = cvt_pk_bf16(b.x, b.y);
  o.w = cvt_pk_bf16(b.z, b.w);
  ((uint4*)out)[i] = o;
}

// ---- LDS-tiled transpose+convert: in [K][N] fp32 -> out [N][K] bf16 ----
__global__ __launch_bounds__(256) void transpose_cvt_kernel(const float* __restrict__ in,
                                                            u16* __restrict__ out,
                                                            int K, int N) {
  __shared__ u16 t[64][66];
  int nbk = K >> 6;
  int bk = blockIdx.x % nbk, bn = blockIdx.x / nbk;
  int k0 = bk << 6, n0 = bn << 6;
  int tid = threadIdx.x;
  #pragma unroll
  for (int i = 0; i < 16; ++i) {
    int idx = i * 256 + tid;
    int kr = idx >> 6, nc = idx & 63;
    t[kr][nc] = f32_to_bf16(in[(size_t)(k0 + kr) * N + n0 + nc]);
  }
  __syncthreads();
  #pragma unroll
  for (int i = 0; i < 16; ++i) {
    int idx = i * 256 + tid;
    int nr = idx >> 6, kc = idx & 63;
    out[(size_t)(n0 + nr) * K + k0 + kc] = t[kc][nr];
  }
}

// ---- bf16 GEMM, A[M][K] @ Bt[N][K]^T, 128x128 tile, BK=64, 4 waves ----
// Double-buffered LDS + counted vmcnt (loads in flight across barriers),
// T2 read swizzle, T1 XCD swizzle. (round-7 best config)
template<int EPI>
__global__ __launch_bounds__(256) void gemm_bt(const u16* __restrict__ A,
                                               const u16* __restrict__ Bt,
                                               float* __restrict__ Cf,
                                               u16* __restrict__ qb,
                                               u16* __restrict__ kb,
                                               u16* __restrict__ vb,
                                               int M, int N, int K, int cpx) {
  __shared__ u16 As[2][128 * 64];
  __shared__ u16 Bs[2][128 * 64];

  int bid = blockIdx.x;
  int wgid = (bid & 7) * cpx + (bid >> 3);
  const int ntn = N >> 7;
  int tm = wgid / ntn, tn = wgid - tm * ntn;
  int mBase = tm << 7, nBase = tn << 7;
  int tid = threadIdx.x;
  int lane = tid & 63, wid = tid >> 6;
  int wr = (wid >> 1) << 6, wc = (wid & 1) << 6;
  int lr = lane & 15, lk = lane >> 4;

  const int nk = K >> 6;

  auto STAGE = [&](int kt, int b) {
    #pragma unroll
    for (int i = 0; i < 4; ++i) {
      int F = i * 4096 + tid * 16;
      int row = F >> 7;
      int cb  = (F & 127) ^ ((row & 7) << 4);
      load_lds16(A + (size_t)(mBase + row) * K + kt * 64 + (cb >> 1), &As[b][F >> 1]);
    }
    #pragma unroll
    for (int i = 0; i < 4; ++i) {
      int F = i * 4096 + tid * 16;
      int row = F >> 7;
      int cb  = (F & 127) ^ ((row & 7) << 4);
      load_lds16(Bt + (size_t)(nBase + row) * K + kt * 64 + (cb >> 1), &Bs[b][F >> 1]);
    }
  };

  f32x4 acc[4][4] = {};

  STAGE(0, 0);
  for (int kt = 0; kt < nk; ++kt) {
    const int cur = kt & 1;
    if (kt + 1 < nk) {
      STAGE(kt + 1, cur ^ 1);
      asm volatile("s_waitcnt vmcnt(8)" ::: "memory");
    } else {
      asm volatile("s_waitcnt vmcnt(0)" ::: "memory");
    }
    __builtin_amdgcn_s_barrier();
    asm volatile("" ::: "memory");

    #pragma unroll
    for (int kk = 0; kk < 2; ++kk) {
      bf16x8 af[4], bfr[4];
      #pragma unroll
      for (int i = 0; i < 4; ++i)
        af[i]  = ldsw(As[cur], wr + i * 16 + lr, kk * 64 + lk * 16);
      #pragma unroll
      for (int i = 0; i < 4; ++i)
        bfr[i] = ldsw(Bs[cur], wc + i * 16 + lr, kk * 64 + lk * 16);
      #pragma unroll
      for (int mi = 0; mi < 4; ++mi)
        #pragma unroll
        for (int ni = 0; ni < 4; ++ni)
          acc[mi][ni] = __builtin_amdgcn_mfma_f32_16x16x32_bf16(af[mi], bfr[ni], acc[mi][ni], 0, 0, 0);
    }

    __builtin_amdgcn_s_barrier();
    asm volatile("" ::: "memory");
  }

  #pragma unroll
  for (int mi = 0; mi < 4; ++mi)
    #pragma unroll
    for (int ni = 0; ni < 4; ++ni)
      #pragma unroll
      for (int j = 0; j < 4; ++j) {
        int m = mBase + wr + mi * 16 + lk * 4 + j;
        int c = nBase + wc + ni * 16 + lr;
        float val = acc[mi][ni][j];
        if (EPI == 0) {
          int s = c / CDIM, rem = c - s * CDIM;
          int h = rem >> 6, d = rem & 63;
          int bb = m >> 10, nn = m & 1023;
          size_t pbase = ((size_t)(bb * NHEAD + h)) << 16;
          if (s == 0)      qb[pbase + (nn << 6) + d] = f32_to_bf16(val * QSCALE);
          else if (s == 1) kb[pbase + (nn << 6) + d] = f32_to_bf16(val);
          else             vb[pbase + ((size_t)d << 10) + nn] = f32_to_bf16(val);
        } else {
          Cf[(size_t)m * N + c] = val;
        }
      }
}

// ---- flash attention v6: v4 structure + counted-vmcnt raw-barrier schedule ----
// block = (pair, qtile of 128 rows), 4 waves x 32 q-rows; 32x32 swapped QK^T;
// in-register softmax+P (cvt_pk + permlane32_swap); K/V^T dbuf, T4 counted
// vmcnt(4) -- never drains to 0 mid-loop (each wave issues exactly 4
// global_load_lds per chunk; vmcnt FIFO => vmcnt(4) = previous stage landed).
__global__ __launch_bounds__(256) void attn_kernel(const u16* __restrict__ q,
                                                   const u16* __restrict__ k,
                                                   const u16* __restrict__ v,
                                                   u16* __restrict__ out) {
  __shared__ u16 Ks[2][64 * 64];
  __shared__ u16 Vs[2][64 * 64];    // V^T chunks: [d=64][k=64]

  int bid = blockIdx.x;
  int wgid = (bid & 7) * 96 + (bid >> 3);   // 768 blocks, 96/XCD -> pairs XCD-local
  int pair = wgid >> 3;
  int qt   = wgid & 7;                      // 8 q-tiles of 128 rows
  int b = pair / NHEAD, hh = pair - b * NHEAD;
  const u16* Kg  = k + ((size_t)pair << 16);
  const u16* Vtb = v + ((size_t)pair << 16);
  int tid = threadIdx.x, lane = tid & 63, wid = tid >> 6;
  int ql = lane & 31, hi = lane >> 5;

  // Q fragments direct to registers (once): row = qt*128 + wid*32 + ql
  const u16* Qrow = q + ((size_t)pair << 16) + (size_t)((qt << 7) + (wid << 5) + ql) * 64;
  bf16x8 qf[4];
  #pragma unroll
  for (int t = 0; t < 4; ++t)
    qf[t] = *(const bf16x8*)(Qrow + t * 16 + hi * 8);

  stage_swz<8192>(Kg, Ks[0], tid);          // 2 loads
  stage_vt(Vtb, Vs[0], 0, tid);             // 2 loads -> 4 outstanding

  float m_ = -1e30f, l_ = 0.f;   // per-lane: q = ql, k-half = hi (l_ partial)
  f32x16 acc0 = {}, acc1 = {};   // O[q][d]: d-tile 0 (0..31), 1 (32..63)

  for (int kc = 0; kc < 16; ++kc) {
    const int cur = kc & 1;
    if (kc < 15) {
      stage_swz<8192>(Kg + ((kc + 1) << 12), Ks[cur ^ 1], tid);   // +2
      stage_vt(Vtb, Vs[cur ^ 1], kc + 1, tid);                    // +2 (8 out)
      asm volatile("s_waitcnt vmcnt(4)" ::: "memory");            // chunk kc landed
    } else {
      asm volatile("s_waitcnt vmcnt(0)" ::: "memory");
    }
    __builtin_amdgcn_s_barrier();           // buf[cur] visible to all waves
    asm volatile("" ::: "memory");

    // S^T = K Q^T : 2 k-tiles x 4 d-steps of 32x32x16
    f32x16 s0 = {}, s1 = {};
    __builtin_amdgcn_s_setprio(1);
    #pragma unroll
    for (int t = 0; t < 4; ++t) {
      bf16x8 k0 = ldsw(Ks[cur], ql,      t * 32 + hi * 16);
      s0 = __builtin_amdgcn_mfma_f32_32x32x16_bf16(k0, qf[t], s0, 0, 0, 0);
      bf16x8 k1 = ldsw(Ks[cur], 32 + ql, t * 32 + hi * 16);
      s1 = __builtin_amdgcn_mfma_f32_32x32x16_bf16(k1, qf[t], s1, 0, 0, 0);
    }
    __builtin_amdgcn_s_setprio(0);

    // per-lane partial max over this lane's 32 k-values (all same q)
    float pm = fmaxf(s0[0], s0[1]);
    #pragma unroll
    for (int r = 2; r < 16; ++r) pm = fmaxf(pm, s0[r]);
    #pragma unroll
    for (int r = 0; r < 16; ++r) pm = fmaxf(pm, s1[r]);

    // defer-max: rescale only when some row's max grew by > 8 (log2 units)
    if (!__all(pm - m_ <= 8.f)) {
      float om = fmaxf(pm, __shfl_xor(pm, 32, 64));
      float newm = fmaxf(m_, om);
      float alpha = exp2f(m_ - newm);
      m_ = newm;
      l_ *= alpha;
      #pragma unroll
      for (int r = 0; r < 16; ++r) {
        int qr = (r & 3) + 8 * (r >> 2) + 4 * hi;
        float ar = __shfl(alpha, qr, 32);
        acc0[r] *= ar;
        acc1[r] *= ar;
      }
    }

    #pragma unroll
    for (int r = 0; r < 16; ++r) s0[r] = exp2f(s0[r] - m_);
    #pragma unroll
    for (int r = 0; r < 16; ++r) s1[r] = exp2f(s1[r] - m_);

    // partial row-sum (this lane's 32 values), tree
    {
      f32x16 ss = s0 + s1;
      float a0 = (ss[0] + ss[1]) + (ss[2] + ss[3]);
      float a1 = (ss[4] + ss[5]) + (ss[6] + ss[7]);
      float a2 = (ss[8] + ss[9]) + (ss[10] + ss[11]);
      float a3 = (ss[12] + ss[13]) + (ss[14] + ss[15]);
      l_ += (a0 + a1) + (a2 + a3);
    }

    // PV: per k-step t, assemble P A-frag in-register and MFMA both d-tiles
    __builtin_amdgcn_s_setprio(1);
    #pragma unroll
    for (int t = 0; t < 4; ++t) {
      const int base = (t & 1) * 8;
      uint32_t wA, wB, wC, wD;
      if (t < 2) {
        wA = cvt_pk_bf16(s0[base + 0], s0[base + 1]);
        wB = cvt_pk_bf16(s0[base + 2], s0[base + 3]);
        wC = cvt_pk_bf16(s0[base + 4], s0[base + 5]);
        wD = cvt_pk_bf16(s0[base + 6], s0[base + 7]);
      } else {
        wA = cvt_pk_bf16(s1[base + 0], s1[base + 1]);
        wB = cvt_pk_bf16(s1[base + 2], s1[base + 3]);
        wC = cvt_pk_bf16(s1[base + 4], s1[base + 5]);
        wD = cvt_pk_bf16(s1[base + 6], s1[base + 7]);
      }
      pl32_swap(wA, wC);
      pl32_swap(wB, wD);
      union { uint32_t u[4]; bf16x8 v8; } pu;
      pu.u[0] = wA; pu.u[1] = wB; pu.u[2] = wC; pu.u[3] = wD;
      bf16x8 v0 = ldsw(Vs[cur], ql,      t * 32 + hi * 16);
      acc0 = __builtin_amdgcn_mfma_f32_32x32x16_bf16(pu.v8, v0, acc0, 0, 0, 0);
      bf16x8 v1 = ldsw(Vs[cur], 32 + ql, t * 32 + hi * 16);
      acc1 = __builtin_amdgcn_mfma_f32_32x32x16_bf16(pu.v8, v1, acc1, 0, 0, 0);
    }
    __builtin_amdgcn_s_setprio(0);

    __builtin_amdgcn_s_barrier();   // all waves' reads of buf[cur] done
    asm volatile("" ::: "memory");  // (next iteration stages into it)
  }

  // epilogue: full row-sum, normalize, write bf16 attn_out [tok][c]
  l_ += __shfl_xor(l_, 32, 64);
  float il = 1.f / l_;
  u16* ob = out + ((size_t)(b * SEQ + (qt << 7) + (wid << 5))) * CDIM + hh * 64 + ql;
  #pragma unroll
  for (int r = 0; r < 16; ++r) {
    int qr = (r & 3) + 8 * (r >> 2) + 4 * hi;
    float ilr = __shfl(il, qr, 32);
    ob[(size_t)qr * CDIM]      = f32_to_bf16(acc0[r] * ilr);
    ob[(size_t)qr * CDIM + 32] = f32_to_bf16(acc1[r] * ilr);
  }
}

extern "C" void kernel_launch(void* const* d_in, const int* in_sizes, int n_in,
                              void* d_out, int out_size, void* d_ws, size_t ws_size,
                              hipStream_t stream) {
  const float* x     = (const float*)d_in[0];
  const float* w_qkv = (const float*)d_in[1];
  const float* w_o   = (const float*)d_in[2];
  float* out = (float*)d_out;

  u16* xb    = (u16*)d_ws;
  u16* wqkvT = xb    + (size_t)MTOK * CDIM;
  u16* woT   = wqkvT + (size_t)NQKV * CDIM;
  u16* qb    = woT   + (size_t)CDIM * CDIM;
  u16* kb    = qb    + (size_t)NPAIR * SEQ * HD;
  u16* vb    = kb    + (size_t)NPAIR * SEQ * HD;   // stored transposed: [pair][d][n]
  u16* ao    = vb    + (size_t)NPAIR * SEQ * HD;

  cvt_x_kernel<<<dim3((MTOK * CDIM) / (256 * 8)), 256, 0, stream>>>(x, xb);
  transpose_cvt_kernel<<<dim3((CDIM / 64) * (NQKV / 64)), 256, 0, stream>>>(w_qkv, wqkvT, CDIM, NQKV);
  transpose_cvt_kernel<<<dim3((CDIM / 64) * (CDIM / 64)), 256, 0, stream>>>(w_o, woT, CDIM, CDIM);

  {
    int nwg = (MTOK / 128) * (NQKV / 128);   // 1152, %8==0
    gemm_bt<0><<<dim3(nwg), 256, 0, stream>>>(
        xb, wqkvT, nullptr, qb, kb, vb, MTOK, NQKV, CDIM, nwg / 8);
  }

  attn_kernel<<<dim3(NPAIR * 8), 256, 0, stream>>>(qb, kb, vb, ao);

  {
    int nwg = (MTOK / 128) * (CDIM / 128);   // 384, %8==0
    gemm_bt<1><<<dim3(nwg), 256, 0, stream>>>(
        ao, woT, out, nullptr, nullptr, nullptr, MTOK, CDIM, CDIM, nwg / 8);
  }
}